// Round 5
// baseline (371.510 us; speedup 1.0000x reference)
//
#include <hip/hip_runtime.h>

typedef unsigned short ushort_t;
typedef __bf16 bf16x8 __attribute__((ext_vector_type(8)));
typedef float f32x4 __attribute__((ext_vector_type(4)));

// ---- problem constants ----
#define NPTS     49152     // B*R*SR = 1*2048*24
#define KNBR     8
#define PTS_BLK  8         // points per block -> 64 neighbor rows
#define NBLOCKS  (NPTS / PTS_BLK)   // 6144

// ---- workspace layout (ushort elements) ----
// swizzled B-fragment layout: Wswz[(k/8)*256*8 + n*8 + (k%8)], K zero-padded
#define W1S_OFF   0         // K=44 ->64  : 8 kb * 2048 = 16384
#define W2S_OFF   16384     // K=256      : 32 kb      = 65536
#define WA1S_OFF  81920     // K=256      : 65536
#define WC1S_OFF  147456    // K=280 ->288: 36 kb      = 73728
#define WS_USHORT 221184

// ---- LDS pool offsets (ushort elements; all byte-offsets 16B-aligned) ----
#define FEAT_O  0            // [64][72]  : 4608
#define H1_O    4608         // [64][264] : 16896
#define CIN_O   21504        // [16][296] : 4736
#define WRAW_O  26240        // float[64] : 128 ushorts
#define WN_O    26368        // float[64] : 128 ushorts
#define POOL_N  26496        // 52992 bytes

__device__ __forceinline__ float b2f(ushort_t u) {
    return __builtin_bit_cast(float, ((unsigned)u) << 16);
}
__device__ __forceinline__ ushort_t f2b(float f) {
    unsigned x = __builtin_bit_cast(unsigned, f);
    unsigned r = x + 0x7fffu + ((x >> 16) & 1u);
    return (ushort_t)(r >> 16);
}

// ------------------------------------------------------------------
// prep: swizzle fp32 weight matrices into bf16 MFMA-B fragment order
// ------------------------------------------------------------------
__global__ __launch_bounds__(256) void prep_swizzle(
    const float* __restrict__ w1, const float* __restrict__ w2,
    const float* __restrict__ wa1, const float* __restrict__ wc1,
    ushort_t* __restrict__ ws)
{
    int idx = blockIdx.x * 256 + threadIdx.x;
    if (idx >= WS_USHORT) return;
    const float* src; int off, srcK, base;
    if (idx < W2S_OFF)        { src = w1;  base = W1S_OFF;  off = idx - W1S_OFF;  srcK = 44;  }
    else if (idx < WA1S_OFF)  { src = w2;  base = W2S_OFF;  off = idx - W2S_OFF;  srcK = 256; }
    else if (idx < WC1S_OFF)  { src = wa1; base = WA1S_OFF; off = idx - WA1S_OFF; srcK = 256; }
    else                      { src = wc1; base = WC1S_OFF; off = idx - WC1S_OFF; srcK = 280; }
    int kb = off >> 11;          // /(256*8)
    int rem = off & 2047;
    int n = rem >> 3, j = rem & 7;
    int k = kb * 8 + j;
    ws[base + off] = (k < srcK) ? f2b(src[k * 256 + n]) : (ushort_t)0;
}

// ------------------------------------------------------------------
// fused aggregator kernel: 8 points / block, 256 threads (4 waves)
// wave w owns M-tile w (16 rows = 2 points) for layers 1-2;
// wave w owns N-chunk w (64 cols) for the branch layers.
// ------------------------------------------------------------------
__global__ __launch_bounds__(256) void pa_main(
    const float* __restrict__ emb,   const float* __restrict__ dists,
    const float* __restrict__ vdirs, const int* __restrict__ mask,
    const float* __restrict__ b1,  const float* __restrict__ b2,
    const float* __restrict__ ba1, const float* __restrict__ wa2,
    const float* __restrict__ ba2, const float* __restrict__ bc1,
    const float* __restrict__ wc2, const float* __restrict__ bc2,
    const ushort_t* __restrict__ ws,  float* __restrict__ out)
{
    __shared__ __align__(16) ushort_t pool[POOL_N];
    ushort_t (*sFeat)[72] = (ushort_t(*)[72])(pool + FEAT_O);  // cols 0..43 feat, rest 0
    ushort_t (*sH1)[264]  = (ushort_t(*)[264])(pool + H1_O);   // layer1 out; later fp32 ah/ch
    ushort_t (*sCin)[296] = (ushort_t(*)[296])(pool + CIN_O);  // rows0..7 agg+PEview; rows8..15 zero
    float* sWraw = (float*)(pool + WRAW_O);
    float* sWn   = (float*)(pool + WN_O);

    const int tid  = threadIdx.x;
    const int lane = tid & 63;
    const int wv   = tid >> 6;        // wave 0..3
    const int n0   = lane & 15;
    const int quad = lane >> 4;
    const int pb   = blockIdx.x * PTS_BLK;   // first global point

    // ================= zero entire LDS pool =================
    {
        uint4* p4 = (uint4*)pool;
        uint4 z; z.x = z.y = z.z = z.w = 0u;
        #pragma unroll
        for (int i = 0; i < 13; i++) {
            int idx = tid + i * 256;
            if (idx < (POOL_N / 8)) p4[idx] = z;   // 3312 uint4 total
        }
    }
    __syncthreads();

    // ================= staging phase A =================
    {   // embedding: 2048 contiguous fp32 per block; thread converts 8 elems
        int g0 = blockIdx.x * 2048 + tid * 8;     // global element index
        int r = tid >> 2, c8 = (tid & 3) * 8;     // dest: sFeat[r][c8..c8+7]
        float4 f0 = *(const float4*)(emb + g0);
        float4 f1 = *(const float4*)(emb + g0 + 4);
        ushort_t v8[8];
        v8[0] = f2b(f0.x); v8[1] = f2b(f0.y); v8[2] = f2b(f0.z); v8[3] = f2b(f0.w);
        v8[4] = f2b(f1.x); v8[5] = f2b(f1.y); v8[6] = f2b(f1.z); v8[7] = f2b(f1.w);
        *(uint4*)&sFeat[r][c8] = *(uint4*)v8;
    }
    if (tid < 64) {   // dists -> d2 weight + PE(dist, L=2)
        int gr = pb * KNBR + tid;
        float x = dists[gr * 3 + 0];
        float y = dists[gr * 3 + 1];
        float z = dists[gr * 3 + 2];
        float d2 = x * x + y * y + z * z;
        float m = (float)mask[gr];
        sWraw[tid] = m / fmaxf(d2, 1e-8f);
        float xs[3] = {x, y, z};
        #pragma unroll
        for (int d = 0; d < 3; d++) {
            #pragma unroll
            for (int l = 0; l < 2; l++) {
                float ang = xs[d] * (float)(1 << l);
                sFeat[tid][32 + d * 4 + l]     = f2b(sinf(ang));
                sFeat[tid][32 + d * 4 + 2 + l] = f2b(cosf(ang));
            }
        }
    }
    if (tid >= 64 && tid < 64 + 192) {  // PE(viewdirs, L=4): 8 pts * 24
        int t = tid - 64;
        int p = t / 24, j = t % 24;
        int d = j >> 3, jj = j & 7, l = jj & 3, isc = jj >> 2;
        float ang = vdirs[(pb + p) * 3 + d] * (float)(1 << l);
        sCin[p][256 + j] = f2b(isc ? cosf(ang) : sinf(ang));
    }
    __syncthreads();

    // ================= staging phase B: normalize neighbor weights =========
    if (tid < 64) {
        int lp = tid >> 3;
        float s = 0.f;
        #pragma unroll
        for (int k = 0; k < 8; k++) s += sWraw[lp * 8 + k];
        sWn[tid] = sWraw[tid] / fmaxf(s, 1e-8f);
    }
    __syncthreads();

    // ================= layer 1: [64x64(K=44)] @ w1 -> h1 [64x256] ==========
    f32x4 acc[16];
    #pragma unroll
    for (int i = 0; i < 16; i++) acc[i] = (f32x4){0.f, 0.f, 0.f, 0.f};
    {
        const ushort_t* aBase = &sFeat[wv * 16 + n0][quad * 8];
        const ushort_t* bBase = ws + W1S_OFF + (quad * 256 + n0) * 8;
        #pragma unroll
        for (int ki = 0; ki < 2; ki++) {
            bf16x8 a = *(const bf16x8*)(aBase + ki * 32);
            #pragma unroll
            for (int nt = 0; nt < 16; nt++) {
                bf16x8 b = *(const bf16x8*)(bBase + ki * 8192 + nt * 128);
                acc[nt] = __builtin_amdgcn_mfma_f32_16x16x32_bf16(a, b, acc[nt], 0, 0, 0);
            }
        }
    }
    {   // epilogue: bias + relu -> sH1 (bf16)  (own rows only, same-wave)
        #pragma unroll
        for (int nt = 0; nt < 16; nt++) {
            int col = nt * 16 + n0;
            float bias = b1[col];
            #pragma unroll
            for (int r = 0; r < 4; r++) {
                int row = wv * 16 + quad * 4 + r;
                sH1[row][col] = f2b(fmaxf(acc[nt][r] + bias, 0.f));
            }
        }
    }

    // ================= layer 2: h1 @ w2 -> h2, fused aggregation ===========
    #pragma unroll
    for (int i = 0; i < 16; i++) acc[i] = (f32x4){0.f, 0.f, 0.f, 0.f};
    {
        const ushort_t* aBase = &sH1[wv * 16 + n0][quad * 8];
        const ushort_t* bBase = ws + W2S_OFF + (quad * 256 + n0) * 8;
        #pragma unroll
        for (int ki = 0; ki < 8; ki++) {
            bf16x8 a = *(const bf16x8*)(aBase + ki * 32);
            #pragma unroll
            for (int nt = 0; nt < 16; nt++) {
                bf16x8 b = *(const bf16x8*)(bBase + ki * 8192 + nt * 128);
                acc[nt] = __builtin_amdgcn_mfma_f32_16x16x32_bf16(a, b, acc[nt], 0, 0, 0);
            }
        }
    }
    {   // epilogue: h2 = relu(acc+b2); agg[p][c] = sum_k wn*h2 ; -> sCin bf16
        float wn0 = sWn[wv * 16 + quad * 4 + 0];
        float wn1 = sWn[wv * 16 + quad * 4 + 1];
        float wn2 = sWn[wv * 16 + quad * 4 + 2];
        float wn3 = sWn[wv * 16 + quad * 4 + 3];
        #pragma unroll
        for (int nt = 0; nt < 16; nt++) {
            int col = nt * 16 + n0;
            float bias = b2[col];
            float s = fmaxf(acc[nt][0] + bias, 0.f) * wn0
                    + fmaxf(acc[nt][1] + bias, 0.f) * wn1
                    + fmaxf(acc[nt][2] + bias, 0.f) * wn2
                    + fmaxf(acc[nt][3] + bias, 0.f) * wn3;
            s += __shfl_xor(s, 16);   // quad0+=quad1 (point 2w), quad2+=quad3 (point 2w+1)
            if (quad == 0)      sCin[2 * wv][col]     = f2b(s);
            else if (quad == 2) sCin[2 * wv + 1][col] = f2b(s);
        }
    }
    __syncthreads();

    // ================= alpha hidden: cin[16x256] @ wa1[:, wv*64 +: 64] =====
    f32x4 acc4[4];
    #pragma unroll
    for (int i = 0; i < 4; i++) acc4[i] = (f32x4){0.f, 0.f, 0.f, 0.f};
    {
        const ushort_t* aBase = &sCin[n0][quad * 8];
        const ushort_t* bBase = ws + WA1S_OFF + (quad * 256 + wv * 64 + n0) * 8;
        #pragma unroll
        for (int ki = 0; ki < 8; ki++) {
            bf16x8 a = *(const bf16x8*)(aBase + ki * 32);
            #pragma unroll
            for (int nt = 0; nt < 4; nt++) {
                bf16x8 b = *(const bf16x8*)(bBase + ki * 8192 + nt * 128);
                acc4[nt] = __builtin_amdgcn_mfma_f32_16x16x32_bf16(a, b, acc4[nt], 0, 0, 0);
            }
        }
    }
    float* sAh = (float*)&sH1[0][0];    // [8][264] fp32 (aliases sH1; all layer-2 reads done)
    {
        #pragma unroll
        for (int nt = 0; nt < 4; nt++) {
            int col = wv * 64 + nt * 16 + n0;
            float bias = ba1[col];
            #pragma unroll
            for (int r = 0; r < 4; r++) {
                int row = quad * 4 + r;
                if (row < 8) sAh[row * 264 + col] = fmaxf(acc4[nt][r] + bias, 0.f);
            }
        }
    }

    // ================= color hidden: cin[16x288] @ wc1[:, wv*64 +: 64] =====
    #pragma unroll
    for (int i = 0; i < 4; i++) acc4[i] = (f32x4){0.f, 0.f, 0.f, 0.f};
    {
        const ushort_t* aBase = &sCin[n0][quad * 8];
        const ushort_t* bBase = ws + WC1S_OFF + (quad * 256 + wv * 64 + n0) * 8;
        #pragma unroll
        for (int ki = 0; ki < 9; ki++) {
            bf16x8 a = *(const bf16x8*)(aBase + ki * 32);
            #pragma unroll
            for (int nt = 0; nt < 4; nt++) {
                bf16x8 b = *(const bf16x8*)(bBase + ki * 8192 + nt * 128);
                acc4[nt] = __builtin_amdgcn_mfma_f32_16x16x32_bf16(a, b, acc4[nt], 0, 0, 0);
            }
        }
    }
    float* sCh = (float*)&sH1[32][0];   // [8][264] fp32, disjoint from sAh region
    {
        #pragma unroll
        for (int nt = 0; nt < 4; nt++) {
            int col = wv * 64 + nt * 16 + n0;
            float bias = bc1[col];
            #pragma unroll
            for (int r = 0; r < 4; r++) {
                int row = quad * 4 + r;
                if (row < 8) sCh[row * 264 + col] = fmaxf(acc4[nt][r] + bias, 0.f);
            }
        }
    }
    __syncthreads();

    // ================= finals: density (wave0), color j (wave 1+j) =========
    {
        int p = lane >> 3, i = lane & 7;
        float s = 0.f;
        if (wv == 0) {
            #pragma unroll 4
            for (int t = 0; t < 32; t++) {
                int col = t * 8 + i;
                s += sAh[p * 264 + col] * wa2[col];
            }
        } else {
            int j = wv - 1;
            #pragma unroll 4
            for (int t = 0; t < 32; t++) {
                int col = t * 8 + i;
                s += sCh[p * 264 + col] * wc2[col * 3 + j];
            }
        }
        s += __shfl_xor(s, 1);
        s += __shfl_xor(s, 2);
        s += __shfl_xor(s, 4);
        if (i == 0) {
            int gp = pb + p;
            if (wv == 0) {
                float yv = s + ba2[0] - 1.0f;
                float dens = (yv > 20.f) ? yv : log1pf(expf(yv));
                out[gp * 4 + 0] = dens;                       // fp32 store
            } else {
                float z = s + bc2[wv - 1];
                float sig = 1.f / (1.f + expf(-z));
                out[gp * 4 + wv] = sig * (1.0f + 2e-3f) - 1e-3f;   // fp32 store
            }
        }
    }
}

extern "C" void kernel_launch(void* const* d_in, const int* in_sizes, int n_in,
                              void* d_out, int out_size, void* d_ws, size_t ws_size,
                              hipStream_t stream) {
    const float* emb   = (const float*)d_in[0];
    const float* dists = (const float*)d_in[1];
    const float* vdir  = (const float*)d_in[2];
    const int*   mask  = (const int*)d_in[3];
    const float* w1    = (const float*)d_in[4];
    const float* b1    = (const float*)d_in[5];
    const float* w2    = (const float*)d_in[6];
    const float* b2    = (const float*)d_in[7];
    const float* wa1   = (const float*)d_in[8];
    const float* ba1   = (const float*)d_in[9];
    const float* wa2   = (const float*)d_in[10];
    const float* ba2   = (const float*)d_in[11];
    const float* wc1   = (const float*)d_in[12];
    const float* bc1   = (const float*)d_in[13];
    const float* wc2   = (const float*)d_in[14];
    const float* bc2   = (const float*)d_in[15];
    ushort_t* ws  = (ushort_t*)d_ws;
    float*    out = (float*)d_out;

    prep_swizzle<<<dim3((WS_USHORT + 255) / 256), dim3(256), 0, stream>>>(w1, w2, wa1, wc1, ws);
    pa_main<<<dim3(NBLOCKS), dim3(256), 0, stream>>>(
        emb, dists, vdir, mask, b1, b2, ba1, wa2, ba2, bc1, wc2, bc2, ws, out);
}

// Round 6
// 252.646 us; speedup vs baseline: 1.4705x; 1.4705x over previous
//
#include <hip/hip_runtime.h>

typedef unsigned short ushort_t;
typedef __bf16 bf16x8 __attribute__((ext_vector_type(8)));
typedef float f32x4 __attribute__((ext_vector_type(4)));

// ---- problem constants ----
#define NPTS   49152     // B*R*SR
#define KNBR   8
#define PTS_A  8         // points per block, kernel A -> 64 neighbor rows
#define NBLK_A (NPTS / PTS_A)    // 6144
#define PTS_B  32        // points per block, kernel B
#define NBLK_B (NPTS / PTS_B)    // 1536

// ---- workspace layout (ushort elements) ----
// swizzled B-fragment layout: Wswz[(k/8)*256*8 + n*8 + (k%8)], K zero-padded
#define W1S_OFF   0         // K=44 ->64
#define W2S_OFF   16384     // K=256
#define WA1S_OFF  81920     // K=256
#define WC1S_OFF  147456    // K=280 ->288
#define WS_WEIGHT 221184
#define AGG_OFF   221184    // agg[49152][256] bf16 = 12.58M ushorts (25.2 MB)

__device__ __forceinline__ float b2f(ushort_t u) {
    return __builtin_bit_cast(float, ((unsigned)u) << 16);
}
__device__ __forceinline__ ushort_t f2b(float f) {
    unsigned x = __builtin_bit_cast(unsigned, f);
    unsigned r = x + 0x7fffu + ((x >> 16) & 1u);
    return (ushort_t)(r >> 16);
}

// ------------------------------------------------------------------
// prep: swizzle fp32 weights into bf16 MFMA-B fragment order.
// idx decomposed so source reads are coalesced (n fastest).
// ------------------------------------------------------------------
__global__ __launch_bounds__(256) void prep_swizzle(
    const float* __restrict__ w1, const float* __restrict__ w2,
    const float* __restrict__ wa1, const float* __restrict__ wc1,
    ushort_t* __restrict__ ws)
{
    int idx = blockIdx.x * 256 + threadIdx.x;
    if (idx >= WS_WEIGHT) return;
    const float* src; int off, srcK, base;
    if (idx < W2S_OFF)        { src = w1;  base = W1S_OFF;  off = idx - W1S_OFF;  srcK = 44;  }
    else if (idx < WA1S_OFF)  { src = w2;  base = W2S_OFF;  off = idx - W2S_OFF;  srcK = 256; }
    else if (idx < WC1S_OFF)  { src = wa1; base = WA1S_OFF; off = idx - WA1S_OFF; srcK = 256; }
    else                      { src = wc1; base = WC1S_OFF; off = idx - WC1S_OFF; srcK = 280; }
    int kb  = off >> 11;          // /(256*8)
    int rem = off & 2047;
    int j = rem >> 8;             // k%8
    int n = rem & 255;
    int k = kb * 8 + j;
    float v = (k < srcK) ? src[k * 256 + n] : 0.f;
    ws[base + kb * 2048 + n * 8 + j] = f2b(v);
}

// ------------------------------------------------------------------
// kernel A: per-neighbor MLP (44->256->256) + weighted aggregation.
// 8 points (64 rows) per block, 4 waves. N-SPLIT: wave w computes ALL
// 64 rows for cols [w*64, w*64+64) -> w1/w2 fragments read exactly
// once per block (no intra-block redundancy).
// ------------------------------------------------------------------
__global__ __launch_bounds__(256) void pa_mlp(
    const float* __restrict__ emb, const float* __restrict__ dists,
    const int* __restrict__ mask,  const float* __restrict__ b1,
    const float* __restrict__ b2,  const ushort_t* __restrict__ ws,
    ushort_t* __restrict__ aggg)
{
    __shared__ __align__(16) ushort_t sFeat[64][72];   // cols 0..43 feat, 44..63 zero K-pad
    __shared__ __align__(16) ushort_t sH1[64][264];    // layer1 out (bf16)
    __shared__ __align__(16) float sWraw[64];
    __shared__ __align__(16) float sWn[64];

    const int tid  = threadIdx.x;
    const int lane = tid & 63;
    const int wv   = tid >> 6;
    const int n0   = lane & 15;
    const int quad = lane >> 4;
    const int pb   = blockIdx.x * PTS_A;
    const int colB = wv * 64;          // wave's N-chunk base

    // ---- staging ----
    {   // embedding: 2048 contiguous fp32 per block -> bf16 cols 0..31
        int g0 = blockIdx.x * 2048 + tid * 8;
        int r = tid >> 2, c8 = (tid & 3) * 8;
        float4 f0 = *(const float4*)(emb + g0);
        float4 f1 = *(const float4*)(emb + g0 + 4);
        ushort_t v8[8];
        v8[0] = f2b(f0.x); v8[1] = f2b(f0.y); v8[2] = f2b(f0.z); v8[3] = f2b(f0.w);
        v8[4] = f2b(f1.x); v8[5] = f2b(f1.y); v8[6] = f2b(f1.z); v8[7] = f2b(f1.w);
        *(uint4*)&sFeat[r][c8] = *(uint4*)v8;
    }
    if (tid < 64) {   // dists -> raw weight + PE(dist,L=2) cols 32..43; zero 44..63
        int gr = pb * KNBR + tid;
        float x = dists[gr * 3 + 0];
        float y = dists[gr * 3 + 1];
        float z = dists[gr * 3 + 2];
        float d2 = x * x + y * y + z * z;
        sWraw[tid] = (float)mask[gr] / fmaxf(d2, 1e-8f);
        float xs[3] = {x, y, z};
        #pragma unroll
        for (int d = 0; d < 3; d++) {
            #pragma unroll
            for (int l = 0; l < 2; l++) {
                float ang = xs[d] * (float)(1 << l);
                sFeat[tid][32 + d * 4 + l]     = f2b(sinf(ang));
                sFeat[tid][32 + d * 4 + 2 + l] = f2b(cosf(ang));
            }
        }
        #pragma unroll
        for (int c = 44; c < 64; c++) sFeat[tid][c] = 0;   // K-pad (cols 64..71 never read)
    }
    __syncthreads();
    if (tid < 64) {   // normalize neighbor weights per point
        int lp = tid >> 3;
        float s = 0.f;
        #pragma unroll
        for (int k = 0; k < 8; k++) s += sWraw[lp * 8 + k];
        sWn[tid] = sWraw[tid] / fmaxf(s, 1e-8f);
    }
    __syncthreads();

    f32x4 acc[16];   // [mt 0..3][nt 0..3]
    #pragma unroll
    for (int i = 0; i < 16; i++) acc[i] = (f32x4){0.f, 0.f, 0.f, 0.f};

    // ---- layer 1: K=64 (44 real) ----
    #pragma unroll
    for (int ki = 0; ki < 2; ki++) {
        bf16x8 a[4];
        #pragma unroll
        for (int mt = 0; mt < 4; mt++)
            a[mt] = *(const bf16x8*)&sFeat[mt * 16 + n0][ki * 32 + quad * 8];
        const ushort_t* bp = ws + W1S_OFF + ki * 8192 + quad * 2048 + (colB + n0) * 8;
        #pragma unroll
        for (int nt = 0; nt < 4; nt++) {
            bf16x8 b = *(const bf16x8*)(bp + nt * 128);
            #pragma unroll
            for (int mt = 0; mt < 4; mt++)
                acc[mt * 4 + nt] = __builtin_amdgcn_mfma_f32_16x16x32_bf16(a[mt], b, acc[mt * 4 + nt], 0, 0, 0);
        }
    }
    {   // epilogue: bias+relu -> sH1 (all rows, own cols)
        #pragma unroll
        for (int nt = 0; nt < 4; nt++) {
            int col = colB + nt * 16 + n0;
            float bias = b1[col];
            #pragma unroll
            for (int mt = 0; mt < 4; mt++)
                #pragma unroll
                for (int r = 0; r < 4; r++)
                    sH1[mt * 16 + quad * 4 + r][col] = f2b(fmaxf(acc[mt * 4 + nt][r] + bias, 0.f));
        }
    }
    __syncthreads();

    // ---- layer 2: K=256, fused aggregation ----
    #pragma unroll
    for (int i = 0; i < 16; i++) acc[i] = (f32x4){0.f, 0.f, 0.f, 0.f};
    #pragma unroll
    for (int ki = 0; ki < 8; ki++) {
        bf16x8 a[4];
        #pragma unroll
        for (int mt = 0; mt < 4; mt++)
            a[mt] = *(const bf16x8*)&sH1[mt * 16 + n0][ki * 32 + quad * 8];
        const ushort_t* bp = ws + W2S_OFF + ki * 8192 + quad * 2048 + (colB + n0) * 8;
        #pragma unroll
        for (int nt = 0; nt < 4; nt++) {
            bf16x8 b = *(const bf16x8*)(bp + nt * 128);
            #pragma unroll
            for (int mt = 0; mt < 4; mt++)
                acc[mt * 4 + nt] = __builtin_amdgcn_mfma_f32_16x16x32_bf16(a[mt], b, acc[mt * 4 + nt], 0, 0, 0);
        }
    }
    {   // epilogue: relu + neighbor-weighted sum -> global agg (bf16)
        #pragma unroll
        for (int mt = 0; mt < 4; mt++) {
            f32x4 wn4 = *(const f32x4*)&sWn[mt * 16 + quad * 4];
            #pragma unroll
            for (int nt = 0; nt < 4; nt++) {
                int col = colB + nt * 16 + n0;
                float bias = b2[col];
                float s = fmaxf(acc[mt * 4 + nt][0] + bias, 0.f) * wn4[0]
                        + fmaxf(acc[mt * 4 + nt][1] + bias, 0.f) * wn4[1]
                        + fmaxf(acc[mt * 4 + nt][2] + bias, 0.f) * wn4[2]
                        + fmaxf(acc[mt * 4 + nt][3] + bias, 0.f) * wn4[3];
                s += __shfl_xor(s, 16);   // quad0+=quad1 (pt 2mt), quad2+=quad3 (pt 2mt+1)
                if ((quad & 1) == 0) {
                    int pt = pb + 2 * mt + (quad >> 1);
                    aggg[(size_t)pt * 256 + col] = f2b(s);
                }
            }
        }
    }
}

// ------------------------------------------------------------------
// kernel B: branch MLPs. 32 points per block (1536 blocks) -> wa1/wc1
// read once per 32 points instead of once per 8. N-split waves.
// ------------------------------------------------------------------
__global__ __launch_bounds__(256) void pa_branch(
    const float* __restrict__ vdirs,
    const float* __restrict__ ba1v, const float* __restrict__ wa2,
    const float* __restrict__ ba2v, const float* __restrict__ bc1v,
    const float* __restrict__ wc2,  const float* __restrict__ bc2v,
    const ushort_t* __restrict__ ws, const ushort_t* __restrict__ aggg,
    float* __restrict__ out)
{
    __shared__ __align__(16) ushort_t sCin[32][296];   // agg(0..255) + PEview(256..279) + 0(280..287)
    __shared__ __align__(16) ushort_t sAh[32][264];    // alpha hidden (bf16)
    __shared__ __align__(16) ushort_t sCh[32][264];    // color hidden (bf16)

    const int tid  = threadIdx.x;
    const int lane = tid & 63;
    const int wv   = tid >> 6;
    const int n0   = lane & 15;
    const int quad = lane >> 4;
    const int pb   = blockIdx.x * PTS_B;
    const int colB = wv * 64;

    // ---- staging ----
    #pragma unroll
    for (int it = 0; it < 4; it++) {   // agg: 32*256 = 8192 ushorts
        int idx = (tid + it * 256) * 8;
        uint4 v = *(const uint4*)(aggg + (size_t)pb * 256 + idx);
        *(uint4*)&sCin[idx >> 8][idx & 255] = v;
    }
    #pragma unroll
    for (int it = 0; it < 3; it++) {   // PE(viewdirs,L=4): 32*24 = 768
        int t = tid + it * 256;
        int p = t / 24, j = t % 24;
        int d = j >> 3, jj = j & 7, l = jj & 3, isc = jj >> 2;
        float ang = vdirs[(pb + p) * 3 + d] * (float)(1 << l);
        sCin[p][256 + j] = f2b(isc ? cosf(ang) : sinf(ang));
    }
    sCin[tid >> 3][280 + (tid & 7)] = 0;   // K-pad cols (32*8 = 256 writes)
    __syncthreads();

    f32x4 acc[8];   // [mt 0..1][nt 0..3]

    // ---- alpha hidden: K=256 ----
    #pragma unroll
    for (int i = 0; i < 8; i++) acc[i] = (f32x4){0.f, 0.f, 0.f, 0.f};
    #pragma unroll
    for (int ki = 0; ki < 8; ki++) {
        bf16x8 a0 = *(const bf16x8*)&sCin[n0][ki * 32 + quad * 8];
        bf16x8 a1 = *(const bf16x8*)&sCin[16 + n0][ki * 32 + quad * 8];
        const ushort_t* bp = ws + WA1S_OFF + ki * 8192 + quad * 2048 + (colB + n0) * 8;
        #pragma unroll
        for (int nt = 0; nt < 4; nt++) {
            bf16x8 b = *(const bf16x8*)(bp + nt * 128);
            acc[nt]     = __builtin_amdgcn_mfma_f32_16x16x32_bf16(a0, b, acc[nt], 0, 0, 0);
            acc[4 + nt] = __builtin_amdgcn_mfma_f32_16x16x32_bf16(a1, b, acc[4 + nt], 0, 0, 0);
        }
    }
    #pragma unroll
    for (int nt = 0; nt < 4; nt++) {
        int col = colB + nt * 16 + n0;
        float bias = ba1v[col];
        #pragma unroll
        for (int mt = 0; mt < 2; mt++)
            #pragma unroll
            for (int r = 0; r < 4; r++)
                sAh[mt * 16 + quad * 4 + r][col] = f2b(fmaxf(acc[mt * 4 + nt][r] + bias, 0.f));
    }

    // ---- color hidden: K=288 (280 real) ----
    #pragma unroll
    for (int i = 0; i < 8; i++) acc[i] = (f32x4){0.f, 0.f, 0.f, 0.f};
    #pragma unroll
    for (int ki = 0; ki < 9; ki++) {
        bf16x8 a0 = *(const bf16x8*)&sCin[n0][ki * 32 + quad * 8];
        bf16x8 a1 = *(const bf16x8*)&sCin[16 + n0][ki * 32 + quad * 8];
        const ushort_t* bp = ws + WC1S_OFF + ki * 8192 + quad * 2048 + (colB + n0) * 8;
        #pragma unroll
        for (int nt = 0; nt < 4; nt++) {
            bf16x8 b = *(const bf16x8*)(bp + nt * 128);
            acc[nt]     = __builtin_amdgcn_mfma_f32_16x16x32_bf16(a0, b, acc[nt], 0, 0, 0);
            acc[4 + nt] = __builtin_amdgcn_mfma_f32_16x16x32_bf16(a1, b, acc[4 + nt], 0, 0, 0);
        }
    }
    #pragma unroll
    for (int nt = 0; nt < 4; nt++) {
        int col = colB + nt * 16 + n0;
        float bias = bc1v[col];
        #pragma unroll
        for (int mt = 0; mt < 2; mt++)
            #pragma unroll
            for (int r = 0; r < 4; r++)
                sCh[mt * 16 + quad * 4 + r][col] = f2b(fmaxf(acc[mt * 4 + nt][r] + bias, 0.f));
    }
    __syncthreads();

    // ---- finals: per wave 8 points; lane = p_local*8 + i; i sums a 32-k chunk ----
    {
        int p = wv * 8 + (lane >> 3);
        int i = lane & 7;
        float s0 = 0.f, s1 = 0.f, s2 = 0.f, s3 = 0.f;
        #pragma unroll
        for (int u = 0; u < 4; u++) {
            int k0 = i * 32 + u * 8;
            ushort_t a8[8], c8[8];
            *(uint4*)a8 = *(const uint4*)&sAh[p][k0];
            *(uint4*)c8 = *(const uint4*)&sCh[p][k0];
            #pragma unroll
            for (int e = 0; e < 8; e++) {
                int k = k0 + e;
                float av = b2f(a8[e]), cv = b2f(c8[e]);
                s0 += av * wa2[k];
                s1 += cv * wc2[k * 3 + 0];
                s2 += cv * wc2[k * 3 + 1];
                s3 += cv * wc2[k * 3 + 2];
            }
        }
        #pragma unroll
        for (int d = 1; d <= 4; d <<= 1) {
            s0 += __shfl_xor(s0, d);
            s1 += __shfl_xor(s1, d);
            s2 += __shfl_xor(s2, d);
            s3 += __shfl_xor(s3, d);
        }
        if (i == 0) {
            int gp = pb + p;
            float yv = s0 + ba2v[0] - 1.0f;
            float4 o;
            o.x = (yv > 20.f) ? yv : log1pf(expf(yv));
            o.y = (1.f / (1.f + expf(-(s1 + bc2v[0])))) * (1.0f + 2e-3f) - 1e-3f;
            o.z = (1.f / (1.f + expf(-(s2 + bc2v[1])))) * (1.0f + 2e-3f) - 1e-3f;
            o.w = (1.f / (1.f + expf(-(s3 + bc2v[2])))) * (1.0f + 2e-3f) - 1e-3f;
            *(float4*)(out + (size_t)gp * 4) = o;
        }
    }
}

extern "C" void kernel_launch(void* const* d_in, const int* in_sizes, int n_in,
                              void* d_out, int out_size, void* d_ws, size_t ws_size,
                              hipStream_t stream) {
    const float* emb   = (const float*)d_in[0];
    const float* dists = (const float*)d_in[1];
    const float* vdir  = (const float*)d_in[2];
    const int*   mask  = (const int*)d_in[3];
    const float* w1    = (const float*)d_in[4];
    const float* b1    = (const float*)d_in[5];
    const float* w2    = (const float*)d_in[6];
    const float* b2    = (const float*)d_in[7];
    const float* wa1   = (const float*)d_in[8];
    const float* ba1   = (const float*)d_in[9];
    const float* wa2   = (const float*)d_in[10];
    const float* ba2   = (const float*)d_in[11];
    const float* wc1   = (const float*)d_in[12];
    const float* bc1   = (const float*)d_in[13];
    const float* wc2   = (const float*)d_in[14];
    const float* bc2   = (const float*)d_in[15];
    ushort_t* ws  = (ushort_t*)d_ws;
    float*    out = (float*)d_out;

    prep_swizzle<<<dim3((WS_WEIGHT + 255) / 256), dim3(256), 0, stream>>>(w1, w2, wa1, wc1, ws);
    pa_mlp<<<dim3(NBLK_A), dim3(256), 0, stream>>>(
        emb, dists, mask, b1, b2, ws, ws + AGG_OFF);
    pa_branch<<<dim3(NBLK_B), dim3(256), 0, stream>>>(
        vdir, ba1, wa2, ba2, bc1, wc2, bc2, ws, ws + AGG_OFF, out);
}

// Round 7
// 247.578 us; speedup vs baseline: 1.5006x; 1.0205x over previous
//
#include <hip/hip_runtime.h>

typedef unsigned short ushort_t;
typedef __bf16 bf16x8 __attribute__((ext_vector_type(8)));
typedef float f32x4 __attribute__((ext_vector_type(4)));

// ---- problem constants ----
#define NPTS   49152     // B*R*SR
#define KNBR   8
#define PTS_A  8         // points per block, kernel A -> 64 neighbor rows
#define NBLK_A (NPTS / PTS_A)    // 6144
#define PTS_B  32        // points per block, kernel B
#define NBLK_B (NPTS / PTS_B)    // 1536

// ---- workspace layout (ushort elements) ----
// swizzled B-fragment layout: Wswz[(k/8)*256*8 + n*8 + (k%8)], K zero-padded
#define W1S_OFF   0         // K=44 ->64
#define W2S_OFF   16384     // K=256
#define WA1S_OFF  81920     // K=256
#define WC1S_OFF  147456    // K=280 ->288
#define WS_WEIGHT 221184
#define AGG_OFF   221184    // agg[49152][256] bf16 = 12.58M ushorts (25.2 MB)

__device__ __forceinline__ float b2f(ushort_t u) {
    return __builtin_bit_cast(float, ((unsigned)u) << 16);
}
// RNE f2b (prep only, cold path)
__device__ __forceinline__ ushort_t f2b(float f) {
    unsigned x = __builtin_bit_cast(unsigned, f);
    unsigned r = x + 0x7fffu + ((x >> 16) & 1u);
    return (ushort_t)(r >> 16);
}
// cheap round-half-up f2b (2 VALU ops; <=0.5 ulp, hot path)
__device__ __forceinline__ ushort_t f2bc(float f) {
    unsigned x = __builtin_bit_cast(unsigned, f);
    return (ushort_t)((x + 0x8000u) >> 16);
}

// ------------------------------------------------------------------
// prep: swizzle fp32 weights into bf16 MFMA-B fragment order.
// ------------------------------------------------------------------
__global__ __launch_bounds__(256) void prep_swizzle(
    const float* __restrict__ w1, const float* __restrict__ w2,
    const float* __restrict__ wa1, const float* __restrict__ wc1,
    ushort_t* __restrict__ ws)
{
    int idx = blockIdx.x * 256 + threadIdx.x;
    if (idx >= WS_WEIGHT) return;
    const float* src; int off, srcK, base;
    if (idx < W2S_OFF)        { src = w1;  base = W1S_OFF;  off = idx - W1S_OFF;  srcK = 44;  }
    else if (idx < WA1S_OFF)  { src = w2;  base = W2S_OFF;  off = idx - W2S_OFF;  srcK = 256; }
    else if (idx < WC1S_OFF)  { src = wa1; base = WA1S_OFF; off = idx - WA1S_OFF; srcK = 256; }
    else                      { src = wc1; base = WC1S_OFF; off = idx - WC1S_OFF; srcK = 280; }
    int kb  = off >> 11;          // /(256*8)
    int rem = off & 2047;
    int j = rem >> 8;             // k%8
    int n = rem & 255;
    int k = kb * 8 + j;
    float v = (k < srcK) ? src[k * 256 + n] : 0.f;
    ws[base + kb * 2048 + n * 8 + j] = f2b(v);
}

// ------------------------------------------------------------------
// kernel A: per-neighbor MLP (44->256->256) + weighted aggregation.
// 8 points (64 rows) / block, 4 waves, N-split. sH1 ALIASES sFeat
// (sFeat dead after layer-1 MFMAs) -> 34.3 KB LDS -> 4 blocks/CU.
// ------------------------------------------------------------------
__global__ __launch_bounds__(256) void pa_mlp(
    const float* __restrict__ emb, const float* __restrict__ dists,
    const int* __restrict__ mask,  const float* __restrict__ b1,
    const float* __restrict__ b2,  const ushort_t* __restrict__ ws,
    ushort_t* __restrict__ aggg)
{
    __shared__ __align__(16) ushort_t uH1[64 * 264];   // phase1: sFeat[64][72]; phase2: sH1[64][264]
    __shared__ __align__(16) float sWraw[64];
    __shared__ __align__(16) float sWn[64];
    ushort_t (*sFeat)[72] = (ushort_t(*)[72])uH1;
    ushort_t (*sH1)[264]  = (ushort_t(*)[264])uH1;

    const int tid  = threadIdx.x;
    const int lane = tid & 63;
    const int wv   = tid >> 6;
    const int n0   = lane & 15;
    const int quad = lane >> 4;
    const int pb   = blockIdx.x * PTS_A;
    const int colB = wv * 64;          // wave's N-chunk base

    // ---- staging ----
    {   // embedding: 2048 contiguous fp32 per block -> bf16 cols 0..31
        int g0 = blockIdx.x * 2048 + tid * 8;
        int r = tid >> 2, c8 = (tid & 3) * 8;
        float4 f0 = *(const float4*)(emb + g0);
        float4 f1 = *(const float4*)(emb + g0 + 4);
        ushort_t v8[8];
        v8[0] = f2bc(f0.x); v8[1] = f2bc(f0.y); v8[2] = f2bc(f0.z); v8[3] = f2bc(f0.w);
        v8[4] = f2bc(f1.x); v8[5] = f2bc(f1.y); v8[6] = f2bc(f1.z); v8[7] = f2bc(f1.w);
        *(uint4*)&sFeat[r][c8] = *(uint4*)v8;
    }
    if (tid < 64) {   // dists -> raw weight + PE(dist,L=2) cols 32..43; zero 44..63
        int gr = pb * KNBR + tid;
        float x = dists[gr * 3 + 0];
        float y = dists[gr * 3 + 1];
        float z = dists[gr * 3 + 2];
        float d2 = x * x + y * y + z * z;
        sWraw[tid] = (float)mask[gr] / fmaxf(d2, 1e-8f);
        float xs[3] = {x, y, z};
        #pragma unroll
        for (int d = 0; d < 3; d++) {
            #pragma unroll
            for (int l = 0; l < 2; l++) {
                float ang = xs[d] * (float)(1 << l);
                sFeat[tid][32 + d * 4 + l]     = f2bc(__sinf(ang));
                sFeat[tid][32 + d * 4 + 2 + l] = f2bc(__cosf(ang));
            }
        }
        #pragma unroll
        for (int c = 44; c < 64; c++) sFeat[tid][c] = 0;   // K-pad
    }
    __syncthreads();
    if (tid < 64) {   // normalize neighbor weights (read after next barrier)
        int lp = tid >> 3;
        float s = 0.f;
        #pragma unroll
        for (int k = 0; k < 8; k++) s += sWraw[lp * 8 + k];
        sWn[tid] = sWraw[tid] / fmaxf(s, 1e-8f);
    }

    f32x4 acc[16];   // [mt 0..3][nt 0..3]
    #pragma unroll
    for (int i = 0; i < 16; i++) acc[i] = (f32x4){0.f, 0.f, 0.f, 0.f};

    // ---- layer 1: K=64 (44 real), reads sFeat ----
    #pragma unroll
    for (int ki = 0; ki < 2; ki++) {
        bf16x8 a[4];
        #pragma unroll
        for (int mt = 0; mt < 4; mt++)
            a[mt] = *(const bf16x8*)&sFeat[mt * 16 + n0][ki * 32 + quad * 8];
        const ushort_t* bp = ws + W1S_OFF + ki * 8192 + quad * 2048 + (colB + n0) * 8;
        #pragma unroll
        for (int nt = 0; nt < 4; nt++) {
            bf16x8 b = *(const bf16x8*)(bp + nt * 128);
            #pragma unroll
            for (int mt = 0; mt < 4; mt++)
                acc[mt * 4 + nt] = __builtin_amdgcn_mfma_f32_16x16x32_bf16(a[mt], b, acc[mt * 4 + nt], 0, 0, 0);
        }
    }
    __syncthreads();   // all sFeat reads complete before overwrite

    {   // epilogue: bias+relu -> sH1 (overwrites sFeat region)
        #pragma unroll
        for (int nt = 0; nt < 4; nt++) {
            int col = colB + nt * 16 + n0;
            float bias = b1[col];
            #pragma unroll
            for (int mt = 0; mt < 4; mt++)
                #pragma unroll
                for (int r = 0; r < 4; r++)
                    sH1[mt * 16 + quad * 4 + r][col] = f2bc(fmaxf(acc[mt * 4 + nt][r] + bias, 0.f));
        }
    }
    __syncthreads();

    // ---- layer 2: K=256, fused aggregation ----
    #pragma unroll
    for (int i = 0; i < 16; i++) acc[i] = (f32x4){0.f, 0.f, 0.f, 0.f};
    #pragma unroll
    for (int ki = 0; ki < 8; ki++) {
        bf16x8 a[4];
        #pragma unroll
        for (int mt = 0; mt < 4; mt++)
            a[mt] = *(const bf16x8*)&sH1[mt * 16 + n0][ki * 32 + quad * 8];
        const ushort_t* bp = ws + W2S_OFF + ki * 8192 + quad * 2048 + (colB + n0) * 8;
        #pragma unroll
        for (int nt = 0; nt < 4; nt++) {
            bf16x8 b = *(const bf16x8*)(bp + nt * 128);
            #pragma unroll
            for (int mt = 0; mt < 4; mt++)
                acc[mt * 4 + nt] = __builtin_amdgcn_mfma_f32_16x16x32_bf16(a[mt], b, acc[mt * 4 + nt], 0, 0, 0);
        }
    }
    {   // epilogue: relu + neighbor-weighted sum -> global agg (bf16)
        #pragma unroll
        for (int mt = 0; mt < 4; mt++) {
            f32x4 wn4 = *(const f32x4*)&sWn[mt * 16 + quad * 4];
            #pragma unroll
            for (int nt = 0; nt < 4; nt++) {
                int col = colB + nt * 16 + n0;
                float bias = b2[col];
                float s = fmaxf(acc[mt * 4 + nt][0] + bias, 0.f) * wn4[0]
                        + fmaxf(acc[mt * 4 + nt][1] + bias, 0.f) * wn4[1]
                        + fmaxf(acc[mt * 4 + nt][2] + bias, 0.f) * wn4[2]
                        + fmaxf(acc[mt * 4 + nt][3] + bias, 0.f) * wn4[3];
                s += __shfl_xor(s, 16);   // quad0+=quad1 (pt 2mt), quad2+=quad3 (pt 2mt+1)
                if ((quad & 1) == 0) {
                    int pt = pb + 2 * mt + (quad >> 1);
                    aggg[(size_t)pt * 256 + col] = f2bc(s);
                }
            }
        }
    }
}

// ------------------------------------------------------------------
// kernel B: branch MLPs, 32 points / block. Alpha accs held in regs
// through color MFMAs; sAh then ALIASES the dead sCin region ->
// 35.8 KB LDS -> 4 blocks/CU. Fused K-loop reads A-frags once.
// ------------------------------------------------------------------
__global__ __launch_bounds__(256) void pa_branch(
    const float* __restrict__ vdirs,
    const float* __restrict__ ba1v, const float* __restrict__ wa2,
    const float* __restrict__ ba2v, const float* __restrict__ bc1v,
    const float* __restrict__ wc2,  const float* __restrict__ bc2v,
    const ushort_t* __restrict__ ws, const ushort_t* __restrict__ aggg,
    float* __restrict__ out)
{
    __shared__ __align__(16) ushort_t reg1[32 * 296];  // sCin; later sAh[32][264]
    __shared__ __align__(16) ushort_t reg2[32 * 264];  // sCh
    ushort_t (*sCin)[296] = (ushort_t(*)[296])reg1;
    ushort_t (*sAh)[264]  = (ushort_t(*)[264])reg1;
    ushort_t (*sCh)[264]  = (ushort_t(*)[264])reg2;

    const int tid  = threadIdx.x;
    const int lane = tid & 63;
    const int wv   = tid >> 6;
    const int n0   = lane & 15;
    const int quad = lane >> 4;
    const int pb   = blockIdx.x * PTS_B;
    const int colB = wv * 64;

    // ---- staging ----
    #pragma unroll
    for (int it = 0; it < 4; it++) {   // agg: 32*256 = 8192 ushorts
        int idx = (tid + it * 256) * 8;
        uint4 v = *(const uint4*)(aggg + (size_t)pb * 256 + idx);
        *(uint4*)&sCin[idx >> 8][idx & 255] = v;
    }
    #pragma unroll
    for (int it = 0; it < 3; it++) {   // PE(viewdirs,L=4): 32*24 = 768
        int t = tid + it * 256;
        int p = t / 24, j = t % 24;
        int d = j >> 3, jj = j & 7, l = jj & 3, isc = jj >> 2;
        float ang = vdirs[(pb + p) * 3 + d] * (float)(1 << l);
        sCin[p][256 + j] = f2bc(isc ? __cosf(ang) : __sinf(ang));
    }
    sCin[tid >> 3][280 + (tid & 7)] = 0;   // K-pad cols
    __syncthreads();

    f32x4 accA[8], accC[8];   // [mt 0..1][nt 0..3]
    #pragma unroll
    for (int i = 0; i < 8; i++) { accA[i] = (f32x4){0.f, 0.f, 0.f, 0.f}; accC[i] = accA[i]; }

    // ---- fused K-loop: alpha (K=256) + color (K=288) share A-frags ----
    #pragma unroll
    for (int ki = 0; ki < 9; ki++) {
        bf16x8 a0 = *(const bf16x8*)&sCin[n0][ki * 32 + quad * 8];
        bf16x8 a1 = *(const bf16x8*)&sCin[16 + n0][ki * 32 + quad * 8];
        if (ki < 8) {
            const ushort_t* bpA = ws + WA1S_OFF + ki * 8192 + quad * 2048 + (colB + n0) * 8;
            #pragma unroll
            for (int nt = 0; nt < 4; nt++) {
                bf16x8 b = *(const bf16x8*)(bpA + nt * 128);
                accA[nt]     = __builtin_amdgcn_mfma_f32_16x16x32_bf16(a0, b, accA[nt], 0, 0, 0);
                accA[4 + nt] = __builtin_amdgcn_mfma_f32_16x16x32_bf16(a1, b, accA[4 + nt], 0, 0, 0);
            }
        }
        const ushort_t* bpC = ws + WC1S_OFF + ki * 8192 + quad * 2048 + (colB + n0) * 8;
        #pragma unroll
        for (int nt = 0; nt < 4; nt++) {
            bf16x8 b = *(const bf16x8*)(bpC + nt * 128);
            accC[nt]     = __builtin_amdgcn_mfma_f32_16x16x32_bf16(a0, b, accC[nt], 0, 0, 0);
            accC[4 + nt] = __builtin_amdgcn_mfma_f32_16x16x32_bf16(a1, b, accC[4 + nt], 0, 0, 0);
        }
    }
    __syncthreads();   // all sCin reads complete before sAh overwrites it

    #pragma unroll
    for (int nt = 0; nt < 4; nt++) {
        int col = colB + nt * 16 + n0;
        float biasA = ba1v[col];
        float biasC = bc1v[col];
        #pragma unroll
        for (int mt = 0; mt < 2; mt++)
            #pragma unroll
            for (int r = 0; r < 4; r++) {
                int row = mt * 16 + quad * 4 + r;
                sAh[row][col] = f2bc(fmaxf(accA[mt * 4 + nt][r] + biasA, 0.f));
                sCh[row][col] = f2bc(fmaxf(accC[mt * 4 + nt][r] + biasC, 0.f));
            }
    }
    __syncthreads();

    // ---- finals: per wave 8 points; lane = p_local*8 + i; i sums a 32-k chunk ----
    {
        int p = wv * 8 + (lane >> 3);
        int i = lane & 7;
        float s0 = 0.f, s1 = 0.f, s2 = 0.f, s3 = 0.f;
        #pragma unroll
        for (int u = 0; u < 4; u++) {
            int k0 = i * 32 + u * 8;
            ushort_t a8[8], c8[8];
            *(uint4*)a8 = *(const uint4*)&sAh[p][k0];
            *(uint4*)c8 = *(const uint4*)&sCh[p][k0];
            #pragma unroll
            for (int e = 0; e < 8; e++) {
                int k = k0 + e;
                float av = b2f(a8[e]), cv = b2f(c8[e]);
                s0 += av * wa2[k];
                s1 += cv * wc2[k * 3 + 0];
                s2 += cv * wc2[k * 3 + 1];
                s3 += cv * wc2[k * 3 + 2];
            }
        }
        #pragma unroll
        for (int d = 1; d <= 4; d <<= 1) {
            s0 += __shfl_xor(s0, d);
            s1 += __shfl_xor(s1, d);
            s2 += __shfl_xor(s2, d);
            s3 += __shfl_xor(s3, d);
        }
        if (i == 0) {
            int gp = pb + p;
            float yv = s0 + ba2v[0] - 1.0f;
            float4 o;
            o.x = (yv > 20.f) ? yv : log1pf(expf(yv));
            o.y = (1.f / (1.f + expf(-(s1 + bc2v[0])))) * (1.0f + 2e-3f) - 1e-3f;
            o.z = (1.f / (1.f + expf(-(s2 + bc2v[1])))) * (1.0f + 2e-3f) - 1e-3f;
            o.w = (1.f / (1.f + expf(-(s3 + bc2v[2])))) * (1.0f + 2e-3f) - 1e-3f;
            *(float4*)(out + (size_t)gp * 4) = o;
        }
    }
}

extern "C" void kernel_launch(void* const* d_in, const int* in_sizes, int n_in,
                              void* d_out, int out_size, void* d_ws, size_t ws_size,
                              hipStream_t stream) {
    const float* emb   = (const float*)d_in[0];
    const float* dists = (const float*)d_in[1];
    const float* vdir  = (const float*)d_in[2];
    const int*   mask  = (const int*)d_in[3];
    const float* w1    = (const float*)d_in[4];
    const float* b1    = (const float*)d_in[5];
    const float* w2    = (const float*)d_in[6];
    const float* b2    = (const float*)d_in[7];
    const float* wa1   = (const float*)d_in[8];
    const float* ba1   = (const float*)d_in[9];
    const float* wa2   = (const float*)d_in[10];
    const float* ba2   = (const float*)d_in[11];
    const float* wc1   = (const float*)d_in[12];
    const float* bc1   = (const float*)d_in[13];
    const float* wc2   = (const float*)d_in[14];
    const float* bc2   = (const float*)d_in[15];
    ushort_t* ws  = (ushort_t*)d_ws;
    float*    out = (float*)d_out;

    prep_swizzle<<<dim3((WS_WEIGHT + 255) / 256), dim3(256), 0, stream>>>(w1, w2, wa1, wc1, ws);
    pa_mlp<<<dim3(NBLK_A), dim3(256), 0, stream>>>(
        emb, dists, mask, b1, b2, ws, ws + AGG_OFF);
    pa_branch<<<dim3(NBLK_B), dim3(256), 0, stream>>>(
        vdir, ba1, wa2, ba2, bc1, wc2, bc2, ws, ws + AGG_OFF, out);
}

// Round 8
// 210.971 us; speedup vs baseline: 1.7609x; 1.1735x over previous
//
#include <hip/hip_runtime.h>

typedef unsigned short ushort_t;
typedef __bf16 bf16x8 __attribute__((ext_vector_type(8)));
typedef float f32x4 __attribute__((ext_vector_type(4)));

// ---- problem constants ----
#define NPTS   49152     // B*R*SR
#define KNBR   8
#define PTS_A  8         // points per block, kernel A -> 64 neighbor rows
#define NBLK_A (NPTS / PTS_A)    // 6144
#define PTS_B  32        // points per block, kernel B
#define NBLK_B (NPTS / PTS_B)    // 1536

// ---- workspace layout (ushort elements) ----
// big weights: Wswz[(k/8)*256*8 + n*8 + (k%8)], K zero-padded
// final weights (N=16 pad): Wf[(k/8)*16*8 + n*8 + (k%8)], K=256
#define W1S_OFF   0         // K=44 ->64
#define W2S_OFF   16384     // K=256
#define WA1S_OFF  81920     // K=256
#define WC1S_OFF  147456    // K=280 ->288
#define WA2S_OFF  221184    // 4096 (wa2 in col 0)
#define WC2S_OFF  225280    // 4096 (wc2 in cols 0..2)
#define WS_WEIGHT 229376
#define AGG_OFF   229376    // agg[49152][256] bf16 = 12.58M ushorts (25.2 MB)

__device__ __forceinline__ float b2f(ushort_t u) {
    return __builtin_bit_cast(float, ((unsigned)u) << 16);
}
// RNE f2b (prep only, cold path)
__device__ __forceinline__ ushort_t f2b(float f) {
    unsigned x = __builtin_bit_cast(unsigned, f);
    unsigned r = x + 0x7fffu + ((x >> 16) & 1u);
    return (ushort_t)(r >> 16);
}
// cheap round-half-up f2b (2 VALU ops, hot path)
__device__ __forceinline__ ushort_t f2bc(float f) {
    unsigned x = __builtin_bit_cast(unsigned, f);
    return (ushort_t)((x + 0x8000u) >> 16);
}

// ------------------------------------------------------------------
// prep: swizzle fp32 weights into bf16 MFMA-B fragment order.
// ------------------------------------------------------------------
__global__ __launch_bounds__(256) void prep_swizzle(
    const float* __restrict__ w1, const float* __restrict__ w2,
    const float* __restrict__ wa1, const float* __restrict__ wc1,
    const float* __restrict__ wa2, const float* __restrict__ wc2,
    ushort_t* __restrict__ ws)
{
    int idx = blockIdx.x * 256 + threadIdx.x;
    if (idx >= WS_WEIGHT) return;

    if (idx >= WA2S_OFF) {   // final-projection matrices, N=16 pad
        int off2 = idx - WA2S_OFF;
        int mat = off2 >> 12;          // 0: wa2, 1: wc2
        int off = off2 & 4095;
        int kb = off >> 7, rem = off & 127;
        int n = rem >> 3, j = rem & 7;
        int k = kb * 8 + j;
        float v = 0.f;
        if (mat == 0) { if (n == 0) v = wa2[k]; }
        else          { if (n < 3)  v = wc2[k * 3 + n]; }
        ws[idx] = f2b(v);
        return;
    }

    const float* src; int off, srcK, base;
    if (idx < W2S_OFF)        { src = w1;  base = W1S_OFF;  off = idx - W1S_OFF;  srcK = 44;  }
    else if (idx < WA1S_OFF)  { src = w2;  base = W2S_OFF;  off = idx - W2S_OFF;  srcK = 256; }
    else if (idx < WC1S_OFF)  { src = wa1; base = WA1S_OFF; off = idx - WA1S_OFF; srcK = 256; }
    else                      { src = wc1; base = WC1S_OFF; off = idx - WC1S_OFF; srcK = 280; }
    int kb  = off >> 11;          // /(256*8)
    int rem = off & 2047;
    int j = rem >> 8;             // k%8
    int n = rem & 255;
    int k = kb * 8 + j;
    float v = (k < srcK) ? src[k * 256 + n] : 0.f;
    ws[base + kb * 2048 + n * 8 + j] = f2b(v);
}

// ------------------------------------------------------------------
// kernel A: per-neighbor MLP (44->256->256) + weighted aggregation.
// 8 points (64 rows) / block, 4 waves, N-split; sH1 aliases sFeat.
// (unchanged from round 7 - stable at ~96 us)
// ------------------------------------------------------------------
__global__ __launch_bounds__(256) void pa_mlp(
    const float* __restrict__ emb, const float* __restrict__ dists,
    const int* __restrict__ mask,  const float* __restrict__ b1,
    const float* __restrict__ b2,  const ushort_t* __restrict__ ws,
    ushort_t* __restrict__ aggg)
{
    __shared__ __align__(16) ushort_t uH1[64 * 264];   // phase1: sFeat[64][72]; phase2: sH1[64][264]
    __shared__ __align__(16) float sWraw[64];
    __shared__ __align__(16) float sWn[64];
    ushort_t (*sFeat)[72] = (ushort_t(*)[72])uH1;
    ushort_t (*sH1)[264]  = (ushort_t(*)[264])uH1;

    const int tid  = threadIdx.x;
    const int lane = tid & 63;
    const int wv   = tid >> 6;
    const int n0   = lane & 15;
    const int quad = lane >> 4;
    const int pb   = blockIdx.x * PTS_A;
    const int colB = wv * 64;

    {   // embedding: 2048 contiguous fp32 per block -> bf16 cols 0..31
        int g0 = blockIdx.x * 2048 + tid * 8;
        int r = tid >> 2, c8 = (tid & 3) * 8;
        float4 f0 = *(const float4*)(emb + g0);
        float4 f1 = *(const float4*)(emb + g0 + 4);
        ushort_t v8[8];
        v8[0] = f2bc(f0.x); v8[1] = f2bc(f0.y); v8[2] = f2bc(f0.z); v8[3] = f2bc(f0.w);
        v8[4] = f2bc(f1.x); v8[5] = f2bc(f1.y); v8[6] = f2bc(f1.z); v8[7] = f2bc(f1.w);
        *(uint4*)&sFeat[r][c8] = *(uint4*)v8;
    }
    if (tid < 64) {   // dists -> raw weight + PE(dist,L=2) cols 32..43; zero 44..63
        int gr = pb * KNBR + tid;
        float x = dists[gr * 3 + 0];
        float y = dists[gr * 3 + 1];
        float z = dists[gr * 3 + 2];
        float d2 = x * x + y * y + z * z;
        sWraw[tid] = (float)mask[gr] / fmaxf(d2, 1e-8f);
        float xs[3] = {x, y, z};
        #pragma unroll
        for (int d = 0; d < 3; d++) {
            #pragma unroll
            for (int l = 0; l < 2; l++) {
                float ang = xs[d] * (float)(1 << l);
                sFeat[tid][32 + d * 4 + l]     = f2bc(__sinf(ang));
                sFeat[tid][32 + d * 4 + 2 + l] = f2bc(__cosf(ang));
            }
        }
        #pragma unroll
        for (int c = 44; c < 64; c++) sFeat[tid][c] = 0;
    }
    __syncthreads();
    if (tid < 64) {
        int lp = tid >> 3;
        float s = 0.f;
        #pragma unroll
        for (int k = 0; k < 8; k++) s += sWraw[lp * 8 + k];
        sWn[tid] = sWraw[tid] / fmaxf(s, 1e-8f);
    }

    f32x4 acc[16];
    #pragma unroll
    for (int i = 0; i < 16; i++) acc[i] = (f32x4){0.f, 0.f, 0.f, 0.f};

    // ---- layer 1: K=64 (44 real) ----
    #pragma unroll
    for (int ki = 0; ki < 2; ki++) {
        bf16x8 a[4];
        #pragma unroll
        for (int mt = 0; mt < 4; mt++)
            a[mt] = *(const bf16x8*)&sFeat[mt * 16 + n0][ki * 32 + quad * 8];
        const ushort_t* bp = ws + W1S_OFF + ki * 8192 + quad * 2048 + (colB + n0) * 8;
        #pragma unroll
        for (int nt = 0; nt < 4; nt++) {
            bf16x8 b = *(const bf16x8*)(bp + nt * 128);
            #pragma unroll
            for (int mt = 0; mt < 4; mt++)
                acc[mt * 4 + nt] = __builtin_amdgcn_mfma_f32_16x16x32_bf16(a[mt], b, acc[mt * 4 + nt], 0, 0, 0);
        }
    }
    __syncthreads();

    {   // epilogue: bias+relu -> sH1 (overwrites sFeat region)
        #pragma unroll
        for (int nt = 0; nt < 4; nt++) {
            int col = colB + nt * 16 + n0;
            float bias = b1[col];
            #pragma unroll
            for (int mt = 0; mt < 4; mt++)
                #pragma unroll
                for (int r = 0; r < 4; r++)
                    sH1[mt * 16 + quad * 4 + r][col] = f2bc(fmaxf(acc[mt * 4 + nt][r] + bias, 0.f));
        }
    }
    __syncthreads();

    // ---- layer 2: K=256, fused aggregation ----
    #pragma unroll
    for (int i = 0; i < 16; i++) acc[i] = (f32x4){0.f, 0.f, 0.f, 0.f};
    #pragma unroll
    for (int ki = 0; ki < 8; ki++) {
        bf16x8 a[4];
        #pragma unroll
        for (int mt = 0; mt < 4; mt++)
            a[mt] = *(const bf16x8*)&sH1[mt * 16 + n0][ki * 32 + quad * 8];
        const ushort_t* bp = ws + W2S_OFF + ki * 8192 + quad * 2048 + (colB + n0) * 8;
        #pragma unroll
        for (int nt = 0; nt < 4; nt++) {
            bf16x8 b = *(const bf16x8*)(bp + nt * 128);
            #pragma unroll
            for (int mt = 0; mt < 4; mt++)
                acc[mt * 4 + nt] = __builtin_amdgcn_mfma_f32_16x16x32_bf16(a[mt], b, acc[mt * 4 + nt], 0, 0, 0);
        }
    }
    {   // epilogue: relu + neighbor-weighted sum -> global agg (bf16)
        #pragma unroll
        for (int mt = 0; mt < 4; mt++) {
            f32x4 wn4 = *(const f32x4*)&sWn[mt * 16 + quad * 4];
            #pragma unroll
            for (int nt = 0; nt < 4; nt++) {
                int col = colB + nt * 16 + n0;
                float bias = b2[col];
                float s = fmaxf(acc[mt * 4 + nt][0] + bias, 0.f) * wn4[0]
                        + fmaxf(acc[mt * 4 + nt][1] + bias, 0.f) * wn4[1]
                        + fmaxf(acc[mt * 4 + nt][2] + bias, 0.f) * wn4[2]
                        + fmaxf(acc[mt * 4 + nt][3] + bias, 0.f) * wn4[3];
                s += __shfl_xor(s, 16);
                if ((quad & 1) == 0) {
                    int pt = pb + 2 * mt + (quad >> 1);
                    aggg[(size_t)pt * 256 + col] = f2bc(s);
                }
            }
        }
    }
}

// ------------------------------------------------------------------
// kernel B: branch MLPs, 32 points / block, 4 waves. Hidden layers
// N-split; final 256->{1,3} projections done with MFMA against
// pre-swizzled wa2/wc2 (N=16 pad). sAh aliases dead sCin.
// ------------------------------------------------------------------
__global__ __launch_bounds__(256) void pa_branch(
    const float* __restrict__ vdirs,
    const float* __restrict__ ba1v, const float* __restrict__ ba2v,
    const float* __restrict__ bc1v, const float* __restrict__ bc2v,
    const ushort_t* __restrict__ ws, const ushort_t* __restrict__ aggg,
    float* __restrict__ out)
{
    __shared__ __align__(16) ushort_t reg1[32 * 296];  // sCin; later sAh[32][264]
    __shared__ __align__(16) ushort_t reg2[32 * 264];  // sCh
    ushort_t (*sCin)[296] = (ushort_t(*)[296])reg1;
    ushort_t (*sAh)[264]  = (ushort_t(*)[264])reg1;
    ushort_t (*sCh)[264]  = (ushort_t(*)[264])reg2;

    const int tid  = threadIdx.x;
    const int lane = tid & 63;
    const int wv   = tid >> 6;
    const int n0   = lane & 15;
    const int quad = lane >> 4;
    const int pb   = blockIdx.x * PTS_B;
    const int colB = wv * 64;

    // ---- staging ----
    #pragma unroll
    for (int it = 0; it < 4; it++) {   // agg: 32*256 = 8192 ushorts
        int idx = (tid + it * 256) * 8;
        uint4 v = *(const uint4*)(aggg + (size_t)pb * 256 + idx);
        *(uint4*)&sCin[idx >> 8][idx & 255] = v;
    }
    #pragma unroll
    for (int it = 0; it < 3; it++) {   // PE(viewdirs,L=4): 32*24 = 768
        int t = tid + it * 256;
        int p = t / 24, j = t % 24;
        int d = j >> 3, jj = j & 7, l = jj & 3, isc = jj >> 2;
        float ang = vdirs[(pb + p) * 3 + d] * (float)(1 << l);
        sCin[p][256 + j] = f2bc(isc ? __cosf(ang) : __sinf(ang));
    }
    sCin[tid >> 3][280 + (tid & 7)] = 0;   // K-pad cols
    __syncthreads();

    f32x4 accA[8], accC[8];   // [mt 0..1][nt 0..3]
    #pragma unroll
    for (int i = 0; i < 8; i++) { accA[i] = (f32x4){0.f, 0.f, 0.f, 0.f}; accC[i] = accA[i]; }

    // ---- alpha hidden: K=256 ----
    #pragma unroll
    for (int ki = 0; ki < 8; ki++) {
        bf16x8 a0 = *(const bf16x8*)&sCin[n0][ki * 32 + quad * 8];
        bf16x8 a1 = *(const bf16x8*)&sCin[16 + n0][ki * 32 + quad * 8];
        const ushort_t* bp = ws + WA1S_OFF + ki * 8192 + quad * 2048 + (colB + n0) * 8;
        #pragma unroll
        for (int nt = 0; nt < 4; nt++) {
            bf16x8 b = *(const bf16x8*)(bp + nt * 128);
            accA[nt]     = __builtin_amdgcn_mfma_f32_16x16x32_bf16(a0, b, accA[nt], 0, 0, 0);
            accA[4 + nt] = __builtin_amdgcn_mfma_f32_16x16x32_bf16(a1, b, accA[4 + nt], 0, 0, 0);
        }
    }
    // ---- color hidden: K=288 (280 real) ----
    #pragma unroll
    for (int ki = 0; ki < 9; ki++) {
        bf16x8 a0 = *(const bf16x8*)&sCin[n0][ki * 32 + quad * 8];
        bf16x8 a1 = *(const bf16x8*)&sCin[16 + n0][ki * 32 + quad * 8];
        const ushort_t* bp = ws + WC1S_OFF + ki * 8192 + quad * 2048 + (colB + n0) * 8;
        #pragma unroll
        for (int nt = 0; nt < 4; nt++) {
            bf16x8 b = *(const bf16x8*)(bp + nt * 128);
            accC[nt]     = __builtin_amdgcn_mfma_f32_16x16x32_bf16(a0, b, accC[nt], 0, 0, 0);
            accC[4 + nt] = __builtin_amdgcn_mfma_f32_16x16x32_bf16(a1, b, accC[4 + nt], 0, 0, 0);
        }
    }
    __syncthreads();   // all sCin reads complete before sAh overwrites it

    #pragma unroll
    for (int nt = 0; nt < 4; nt++) {
        int col = colB + nt * 16 + n0;
        float biasA = ba1v[col];
        float biasC = bc1v[col];
        #pragma unroll
        for (int mt = 0; mt < 2; mt++)
            #pragma unroll
            for (int r = 0; r < 4; r++) {
                int row = mt * 16 + quad * 4 + r;
                sAh[row][col] = f2bc(fmaxf(accA[mt * 4 + nt][r] + biasA, 0.f));
                sCh[row][col] = f2bc(fmaxf(accC[mt * 4 + nt][r] + biasC, 0.f));
            }
    }
    __syncthreads();

    // ---- finals via MFMA: wave0/1 alpha m-tiles, wave2/3 color m-tiles ----
    {
        const int isColor = wv >> 1;
        const int baseM   = (wv & 1) * 16;
        const ushort_t* A = isColor ? &sCh[0][0] : &sAh[0][0];
        const ushort_t* B = ws + (isColor ? WC2S_OFF : WA2S_OFF);
        f32x4 acc4 = (f32x4){0.f, 0.f, 0.f, 0.f};
        #pragma unroll
        for (int ki = 0; ki < 8; ki++) {
            bf16x8 a = *(const bf16x8*)(A + (baseM + n0) * 264 + ki * 32 + quad * 8);
            bf16x8 b = *(const bf16x8*)(B + ki * 512 + quad * 128 + n0 * 8);
            acc4 = __builtin_amdgcn_mfma_f32_16x16x32_bf16(a, b, acc4, 0, 0, 0);
        }
        if (!isColor) {
            if (n0 == 0) {
                float ba2s = ba2v[0];
                #pragma unroll
                for (int r = 0; r < 4; r++) {
                    int gp = pb + baseM + quad * 4 + r;
                    float yv = acc4[r] + ba2s - 1.0f;
                    out[(size_t)gp * 4] = (yv > 20.f) ? yv : log1pf(expf(yv));
                }
            }
        } else {
            if (n0 < 3) {
                float bc2s = bc2v[n0];
                #pragma unroll
                for (int r = 0; r < 4; r++) {
                    int gp = pb + baseM + quad * 4 + r;
                    float sig = 1.f / (1.f + expf(-(acc4[r] + bc2s)));
                    out[(size_t)gp * 4 + 1 + n0] = sig * (1.0f + 2e-3f) - 1e-3f;
                }
            }
        }
    }
}

extern "C" void kernel_launch(void* const* d_in, const int* in_sizes, int n_in,
                              void* d_out, int out_size, void* d_ws, size_t ws_size,
                              hipStream_t stream) {
    const float* emb   = (const float*)d_in[0];
    const float* dists = (const float*)d_in[1];
    const float* vdir  = (const float*)d_in[2];
    const int*   mask  = (const int*)d_in[3];
    const float* w1    = (const float*)d_in[4];
    const float* b1    = (const float*)d_in[5];
    const float* w2    = (const float*)d_in[6];
    const float* b2    = (const float*)d_in[7];
    const float* wa1   = (const float*)d_in[8];
    const float* ba1   = (const float*)d_in[9];
    const float* wa2   = (const float*)d_in[10];
    const float* ba2   = (const float*)d_in[11];
    const float* wc1   = (const float*)d_in[12];
    const float* bc1   = (const float*)d_in[13];
    const float* wc2   = (const float*)d_in[14];
    const float* bc2   = (const float*)d_in[15];
    ushort_t* ws  = (ushort_t*)d_ws;
    float*    out = (float*)d_out;

    prep_swizzle<<<dim3((WS_WEIGHT + 255) / 256), dim3(256), 0, stream>>>(
        w1, w2, wa1, wc1, wa2, wc2, ws);
    pa_mlp<<<dim3(NBLK_A), dim3(256), 0, stream>>>(
        emb, dists, mask, b1, b2, ws, ws + AGG_OFF);
    pa_branch<<<dim3(NBLK_B), dim3(256), 0, stream>>>(
        vdir, ba1, ba2, bc1, bc2, ws, ws + AGG_OFF, out);
}